// Round 5
// baseline (1088.442 us; speedup 1.0000x reference)
//
#include <hip/hip_runtime.h>
#include <cmath>

namespace {
constexpr int kNZ = 300, kNX = 400;
constexpr int kNPML = 32;
constexpr int kNZP = 364, kNXP = 464;        // padded physical grid
constexpr int kNSTEPS = 200, kNSHOTS = 2;
constexpr int kSRC_Z = 34, kREC_Z = 34;      // NPML + 2
constexpr float kDT = 0.001f;
constexpr float kINV_DX = 100.0f;            // 1/DX

// temporal blocking
constexpr int kT = 4;                         // steps per dispatch
constexpr int kTILE = 48;                     // loaded tile (with halo)
constexpr int kTT = kTILE * kTILE;            // 2304
constexpr int kHALO = 2 * kT;                 // 8
constexpr int kINT = kTILE - 2 * kHALO;       // 32 interior
constexpr int kTI = (kNZP + kINT - 1) / kINT; // 12 tile rows
constexpr int kTJ = (kNXP + kINT - 1) / kINT; // 15 tile cols
constexpr int kNTILES = kTI * kTJ;            // 180
constexpr int kBLOCKS = kNTILES * kNSHOTS;    // 360
constexpr int kPAIRS = kNSTEPS / kT;          // 50 dispatches

// guarded global layout: guard 8 top/left, enough bottom/right for overhang
constexpr int kGR = 8 + kNZP + 28;            // 400 rows  (max guarded row 399)
constexpr int kGC = 8 + kNXP + 24;            // 496 cols  (max guarded col 495)
constexpr int kGC4 = kGC / 4;                 // 124
constexpr int kNG = kGR * kGC;                // 198400
}  // namespace

// ws layout (floats):
//   moduli: [dtr | damp | lam | mu | l2m]  5*kNG  (zero outside physical grid)
//   fields: buf[2][shot][5][kNG]           20*kNG (guard cells stay exactly 0)
//   loss[1]                                @ 25*kNG
// Moduli premultiplied by DT/DX exactly as rounds 2-4 (bit-exact formulas).

__global__ void fwi_init_kernel(const float* __restrict__ Vp,
                                const float* __restrict__ Vs,
                                const float* __restrict__ Den,
                                float* __restrict__ ws) {
    float* dtrA  = ws;
    float* dampA = ws + kNG;
    float* lamA  = ws + 2 * kNG;
    float* muA   = ws + 3 * kNG;
    float* l2mA  = ws + 4 * kNG;
    float* fld   = ws + 5 * kNG;
    float* lossp = ws + 25 * kNG;

    const int gtid = blockIdx.x * blockDim.x + threadIdx.x;
    const int gstride = gridDim.x * blockDim.x;
    for (int g = gtid; g < kNG; g += gstride) {
        const int gr = g / kGC;
        const int gc = g - gr * kGC;
        const int i = gr - 8;            // padded-grid row
        const int j = gc - 8;            // padded-grid col
        float vdtr = 0.0f, vdamp = 0.0f, vlam = 0.0f, vmu = 0.0f, vl2m = 0.0f;
        if (i >= 0 && i < kNZP && j >= 0 && j < kNXP) {
            int iz = i - kNPML; iz = iz < 0 ? 0 : (iz > kNZ - 1 ? kNZ - 1 : iz);
            int jx = j - kNPML; jx = jx < 0 ? 0 : (jx > kNX - 1 ? kNX - 1 : jx);
            const float vp  = Vp[iz * kNX + jx];
            const float vs  = Vs[iz * kNX + jx];
            const float rho = Den[iz * kNX + jx];
            const float m = vs * vs * rho * 1e-6f;
            const float l = (vp * vp - 2.0f * vs * vs) * rho * 1e-6f;
            const float sc = kDT * kINV_DX;
            float dz = fmaxf((float)(kNPML - i), (float)(i - (kNZP - 1 - kNPML)));
            dz = fminf(fmaxf(dz, 0.0f), (float)kNPML) * (1.0f / kNPML);
            float dxx = fmaxf((float)(kNPML - j), (float)(j - (kNXP - 1 - kNPML)));
            dxx = fminf(fmaxf(dxx, 0.0f), (float)kNPML) * (1.0f / kNPML);
            vdamp = expf(-0.1f * (dz * dz + dxx * dxx));
            vdtr  = kDT / rho * kINV_DX;
            vlam  = l * sc;
            vmu   = m * sc;
            vl2m  = (l + 2.0f * m) * sc;
        }
        dtrA[g] = vdtr; dampA[g] = vdamp; lamA[g] = vlam; muA[g] = vmu; l2mA[g] = vl2m;
    }
    for (int c = gtid; c < 20 * kNG; c += gstride) fld[c] = 0.0f;
    if (gtid == 0) lossp[0] = 0.0f;
}

// T=4 timesteps per dispatch; 3x3 cells/thread in registers, LDS for edge
// exchange. All global traffic is coalesced float4 via cooperative LDS
// staging (moduli first, then fields reuse the same LDS buffer) and a
// coalesced interior writeback at the end. Numerics identical to round 4.
__global__ __launch_bounds__(256, 2) void fwi_step_kernel(
    float* __restrict__ ws, const float* __restrict__ Stf,
    const int* __restrict__ Shot_ids, int pair) {
    __shared__ float LBUF[5 * kTT];   // 46 KB
    float* Lvx  = LBUF;
    float* Lvz  = LBUF + kTT;
    float* Lsxx = LBUF + 2 * kTT;
    float* Lszz = LBUF + 3 * kTT;
    float* Lsxz = LBUF + 4 * kTT;

    float* fld   = ws + 5 * kNG;
    float* lossp = ws + 25 * kNG;

    const int b  = blockIdx.x;
    const int s  = b / kNTILES;
    const int tb = b - s * kNTILES;
    const int TI = tb / kTJ;
    const int TJ = tb - TI * kTJ;

    const int tid = threadIdx.x;
    const int tx = tid & 15;
    const int ty = tid >> 4;
    const int lr0 = 3 * ty;                    // patch rows lr0..lr0+2 in tile
    const int lc0 = 3 * tx;
    const int lbase = lr0 * kTILE + lc0;

    const int p = pair & 1;
    const float* Fc = fld + (p * kNSHOTS + s) * 5 * kNG;
    float*       Fn = fld + ((1 - p) * kNSHOTS + s) * 5 * kNG;

    const int id  = Shot_ids[s];
    const int sxp = kNPML + 20 + id * ((kNX - 40) / kNSHOTS);
    float st[kT];
#pragma unroll
    for (int k = 0; k < kT; ++k) st[k] = Stf[id * kNSTEPS + kT * pair + k] * kDT;

    // float4 index of the loaded tile origin in the guarded arrays
    const int base4 = TI * kINT * kGC4 + TJ * (kINT / 4);

    // ---- stage moduli through LDS (coalesced), pull 3x3 into registers ----
    for (int a = 0; a < 5; ++a) {
        const float4* __restrict__ src = (const float4*)(ws + (size_t)a * kNG);
        float4* dst = (float4*)(LBUF + a * kTT);
        for (int idx = tid; idx < kTT / 4; idx += 256) {
            const int row = idx / (kTILE / 4);
            const int c4  = idx - row * (kTILE / 4);
            dst[idx] = src[base4 + row * kGC4 + c4];
        }
    }
    __syncthreads();

    float rdtr[3][3], rdamp[3][3], rlam[3][3], rmu[3][3], rl2m[3][3];
    float smf[3][3], recm[3][3];
#pragma unroll
    for (int r = 0; r < 3; ++r) {
#pragma unroll
        for (int c = 0; c < 3; ++c) {
            const int l = lbase + r * kTILE + c;
            rdtr[r][c]  = LBUF[l];
            rdamp[r][c] = LBUF[kTT + l];
            rlam[r][c]  = LBUF[2 * kTT + l];
            rmu[r][c]   = LBUF[3 * kTT + l];
            rl2m[r][c]  = LBUF[4 * kTT + l];
            const int prow = TI * kINT - kHALO + lr0 + r;   // padded-grid row
            const int pcol = TJ * kINT - kHALO + lc0 + c;
            smf[r][c]  = (prow == kSRC_Z && pcol == sxp) ? 1.0f : 0.0f;
            const bool inter = (lr0 + r >= kHALO) && (lr0 + r < kHALO + kINT) &&
                               (lc0 + c >= kHALO) && (lc0 + c < kHALO + kINT);
            recm[r][c] = (inter && prow == kREC_Z &&
                          (unsigned)(pcol - kNPML) < (unsigned)kNX) ? 1.0f : 0.0f;
        }
    }
    __syncthreads();   // everyone done reading moduli before LBUF is reused

    // ---- stage fields into LDS (coalesced) ----
    for (int a = 0; a < 5; ++a) {
        const float4* __restrict__ src = (const float4*)(Fc + (size_t)a * kNG);
        float4* dst = (float4*)(LBUF + a * kTT);
        for (int idx = tid; idx < kTT / 4; idx += 256) {
            const int row = idx / (kTILE / 4);
            const int c4  = idx - row * (kTILE / 4);
            dst[idx] = src[base4 + row * kGC4 + c4];
        }
    }
    __syncthreads();

    float vx[3][3], vz[3][3], sxx[3][3], szz[3][3], sxz[3][3];
#pragma unroll
    for (int r = 0; r < 3; ++r) {
#pragma unroll
        for (int c = 0; c < 3; ++c) {
            const int l = lbase + r * kTILE + c;
            vx[r][c]  = Lvx[l];
            vz[r][c]  = Lvz[l];
            sxx[r][c] = Lsxx[l];
            szz[r][c] = Lszz[l];
            sxz[r][c] = Lsxz[l];
        }
    }

    float rsum = 0.0f;
#pragma unroll
    for (int k = 0; k < kT; ++k) {
        // ---- velocity phase (reads stresses; writes vx,vz) ----
#pragma unroll
        for (int r = 0; r < 3; ++r) {
#pragma unroll
            for (int c = 0; c < 3; ++c) {
                const int l = lbase + r * kTILE + c;
                const float sxxC = sxx[r][c];
                const float sxzC = sxz[r][c];
                const float szzC = szz[r][c];
                const float sxxR = (c < 2) ? sxx[r][c + 1] : Lsxx[l + 1];
                const float sxzU = (r > 0) ? sxz[r - 1][c] : Lsxz[l - kTILE];
                const float sxzL = (c > 0) ? sxz[r][c - 1] : Lsxz[l - 1];
                const float szzD = (r < 2) ? szz[r + 1][c] : Lszz[l + kTILE];
                const float nvx = (vx[r][c] + rdtr[r][c] * ((sxxR - sxxC) + (sxzC - sxzU))) * rdamp[r][c];
                const float nvz = (vz[r][c] + rdtr[r][c] * ((sxzC - sxzL) + (szzD - szzC))) * rdamp[r][c];
                vx[r][c] = nvx;
                vz[r][c] = nvz;
                rsum += recm[r][c] * nvx * nvx;
            }
        }
        // publish velocity edges consumed by neighbors
#pragma unroll
        for (int e = 0; e < 3; ++e) {
            Lvx[lbase + e]             = vx[0][e];  // top row
            Lvx[lbase + e * kTILE + 2] = vx[e][2];  // right col
            Lvz[lbase + 2 * kTILE + e] = vz[2][e];  // bottom row
            Lvz[lbase + e * kTILE]     = vz[e][0];  // left col
        }
        __syncthreads();
        // ---- stress phase (reads velocities; writes stresses; source) ----
#pragma unroll
        for (int r = 0; r < 3; ++r) {
#pragma unroll
            for (int c = 0; c < 3; ++c) {
                const int l = lbase + r * kTILE + c;
                const float vxC = vx[r][c];
                const float vzC = vz[r][c];
                const float vxL = (c > 0) ? vx[r][c - 1] : Lvx[l - 1];
                const float vxD = (r < 2) ? vx[r + 1][c] : Lvx[l + kTILE];
                const float vzU = (r > 0) ? vz[r - 1][c] : Lvz[l - kTILE];
                const float vzR = (c < 2) ? vz[r][c + 1] : Lvz[l + 1];
                const float dvx = vxC - vxL;
                const float dvz = vzC - vzU;
                const float dmp = rdamp[r][c];
                float nsxx = (sxx[r][c] + (rl2m[r][c] * dvx + rlam[r][c] * dvz)) * dmp;
                float nszz = (szz[r][c] + (rlam[r][c] * dvx + rl2m[r][c] * dvz)) * dmp;
                float nsxz = (sxz[r][c] + rmu[r][c] * ((vxD - vxC) + (vzR - vzC))) * dmp;
                const float adds = smf[r][c] * st[k];
                nsxx += adds;
                nszz += adds;
                sxx[r][c] = nsxx;
                szz[r][c] = nszz;
                sxz[r][c] = nsxz;
            }
        }
        // publish stress edges consumed by neighbors
#pragma unroll
        for (int e = 0; e < 3; ++e) {
            Lsxx[lbase + e * kTILE]     = sxx[e][0];  // left col
            Lszz[lbase + e]             = szz[0][e];  // top row
            Lsxz[lbase + 2 * kTILE + e] = sxz[2][e];  // bottom row
            Lsxz[lbase + e * kTILE + 2] = sxz[e][2];  // right col
        }
        __syncthreads();
    }

    // ---- dump final registers to LDS, then coalesced interior writeback ----
#pragma unroll
    for (int r = 0; r < 3; ++r) {
#pragma unroll
        for (int c = 0; c < 3; ++c) {
            const int l = lbase + r * kTILE + c;
            Lvx[l]  = vx[r][c];
            Lvz[l]  = vz[r][c];
            Lsxx[l] = sxx[r][c];
            Lszz[l] = szz[r][c];
            Lsxz[l] = sxz[r][c];
        }
    }
    __syncthreads();
    {
        const int introw0 = TI * kINT + kHALO;          // guarded row of interior
        const int intc4   = (TJ * kINT + kHALO) >> 2;   // float4 col of interior
        const int r  = tid >> 3;                        // 0..31
        const int c4 = tid & 7;                         // 0..7
#pragma unroll
        for (int f = 0; f < 5; ++f) {
            float4* dst = (float4*)(Fn + (size_t)f * kNG);
            const float4* src = (const float4*)(LBUF + f * kTT);
            dst[(introw0 + r) * kGC4 + intc4 + c4] =
                src[(kHALO + r) * (kTILE / 4) + (kHALO / 4) + c4];
        }
    }

    // one atomic per wave for the recorder energy
    for (int off = 32; off > 0; off >>= 1) rsum += __shfl_down(rsum, off, 64);
    if ((threadIdx.x & 63) == 0 && rsum != 0.0f) atomicAdd(lossp, rsum);
}

__global__ void fwi_finish_kernel(const float* __restrict__ ws,
                                  float* __restrict__ out) {
    out[0] = 0.5f * ws[25 * kNG];
}

extern "C" void kernel_launch(void* const* d_in, const int* in_sizes, int n_in,
                              void* d_out, int out_size, void* d_ws, size_t ws_size,
                              hipStream_t stream) {
    const float* Vp  = (const float*)d_in[0];
    const float* Vs  = (const float*)d_in[1];
    const float* Den = (const float*)d_in[2];
    const float* Stf = (const float*)d_in[3];
    // d_in[4] = Mask (all-ones; identity in forward value) -- unused
    const int* Shot_ids = (const int*)d_in[5];
    float* out = (float*)d_out;
    float* ws  = (float*)d_ws;

    fwi_init_kernel<<<512, 256, 0, stream>>>(Vp, Vs, Den, ws);
    for (int pair = 0; pair < kPAIRS; ++pair) {
        fwi_step_kernel<<<kBLOCKS, 256, 0, stream>>>(ws, Stf, Shot_ids, pair);
    }
    fwi_finish_kernel<<<1, 1, 0, stream>>>(ws, out);
}

// Round 7
// 937.761 us; speedup vs baseline: 1.1607x; 1.1607x over previous
//
#include <hip/hip_runtime.h>
#include <cmath>

namespace {
constexpr int kNZ = 300, kNX = 400;
constexpr int kNPML = 32;
constexpr int kNZP = 364, kNXP = 464;        // padded physical grid
constexpr int kNSTEPS = 200, kNSHOTS = 2;
constexpr int kSRC_Z = 34, kREC_Z = 34;      // NPML + 2
constexpr float kDT = 0.001f;
constexpr float kINV_DX = 100.0f;            // 1/DX

// temporal blocking: T=4 steps, 32x32 tile, halo 8, 16x16 interior
constexpr int kT = 4;
constexpr int kTILE = 32;
constexpr int kTT = kTILE * kTILE;            // 1024
constexpr int kHALO = 2 * kT;                 // 8
constexpr int kINT = kTILE - 2 * kHALO;       // 16
constexpr int kTI = (kNZP + kINT - 1) / kINT; // 23
constexpr int kTJ = (kNXP + kINT - 1) / kINT; // 29
constexpr int kNTILES = kTI * kTJ;            // 667
constexpr int kBLOCKS = kNTILES * kNSHOTS;    // 1334  (~5.2 blocks/CU)
constexpr int kPAIRS = kNSTEPS / kT;          // 50 dispatches

// guarded global layout: guard 8 top/left + overhang space bottom/right
constexpr int kGR = 400;                      // max guarded row used: 383
constexpr int kGC = 496;                      // max guarded col used: 479
constexpr int kGC4 = kGC / 4;                 // 124
constexpr int kNG = kGR * kGC;                // 198400
}  // namespace

// ws layout (floats):
//   moduli: [dtr | damp | lam | mu | l2m]  5*kNG  (zero outside physical grid)
//   fields: buf[2][shot][5][kNG]           20*kNG (guard cells stay exactly 0)
//   loss[1]                                @ 25*kNG
// Moduli premultiplied by DT/DX exactly as rounds 2-6 (bit-exact formulas).

__global__ void fwi_init_kernel(const float* __restrict__ Vp,
                                const float* __restrict__ Vs,
                                const float* __restrict__ Den,
                                float* __restrict__ ws) {
    float* dtrA  = ws;
    float* dampA = ws + kNG;
    float* lamA  = ws + 2 * kNG;
    float* muA   = ws + 3 * kNG;
    float* l2mA  = ws + 4 * kNG;
    float* fld   = ws + 5 * kNG;
    float* lossp = ws + 25 * kNG;

    const int gtid = blockIdx.x * blockDim.x + threadIdx.x;
    const int gstride = gridDim.x * blockDim.x;
    for (int g = gtid; g < kNG; g += gstride) {
        const int gr = g / kGC;
        const int gc = g - gr * kGC;
        const int i = gr - 8;            // padded-grid row
        const int j = gc - 8;            // padded-grid col
        float vdtr = 0.0f, vdamp = 0.0f, vlam = 0.0f, vmu = 0.0f, vl2m = 0.0f;
        if (i >= 0 && i < kNZP && j >= 0 && j < kNXP) {
            int iz = i - kNPML; iz = iz < 0 ? 0 : (iz > kNZ - 1 ? kNZ - 1 : iz);
            int jx = j - kNPML; jx = jx < 0 ? 0 : (jx > kNX - 1 ? kNX - 1 : jx);
            const float vp  = Vp[iz * kNX + jx];
            const float vs  = Vs[iz * kNX + jx];
            const float rho = Den[iz * kNX + jx];
            const float m = vs * vs * rho * 1e-6f;
            const float l = (vp * vp - 2.0f * vs * vs) * rho * 1e-6f;
            const float sc = kDT * kINV_DX;
            float dz = fmaxf((float)(kNPML - i), (float)(i - (kNZP - 1 - kNPML)));
            dz = fminf(fmaxf(dz, 0.0f), (float)kNPML) * (1.0f / kNPML);
            float dxx = fmaxf((float)(kNPML - j), (float)(j - (kNXP - 1 - kNPML)));
            dxx = fminf(fmaxf(dxx, 0.0f), (float)kNPML) * (1.0f / kNPML);
            vdamp = expf(-0.1f * (dz * dz + dxx * dxx));
            vdtr  = kDT / rho * kINV_DX;
            vlam  = l * sc;
            vmu   = m * sc;
            vl2m  = (l + 2.0f * m) * sc;
        }
        dtrA[g] = vdtr; dampA[g] = vdamp; lamA[g] = vlam; muA[g] = vmu; l2mA[g] = vl2m;
    }
    for (int c = gtid; c < 20 * kNG; c += gstride) fld[c] = 0.0f;
    if (gtid == 0) lossp[0] = 0.0f;
}

// T=4 steps per dispatch, 32x32 tile, 2x2 cells/thread in registers with a
// full-patch LDS mirror for neighbor exchange. Single coalesced staging phase
// (fields + moduli, one barrier). 1334 blocks, 4 blocks/CU resident.
// Tile-border cells read garbage (OOB/wrapped LDS) but the halo-8 dependency
// cone keeps the 16x16 interior exact at every micro-step.
__global__ __launch_bounds__(256, 4) void fwi_step_kernel(
    float* __restrict__ ws, const float* __restrict__ Stf,
    const int* __restrict__ Shot_ids, int pair) {
    __shared__ float LBUF[10 * kTT];   // 40 KB: 5 fields + 5 moduli
    float* Lvx  = LBUF;
    float* Lvz  = LBUF + kTT;
    float* Lsxx = LBUF + 2 * kTT;
    float* Lszz = LBUF + 3 * kTT;
    float* Lsxz = LBUF + 4 * kTT;

    float* fld   = ws + 5 * kNG;
    float* lossp = ws + 25 * kNG;

    const int b  = blockIdx.x;
    const int s  = b / kNTILES;
    const int tb = b - s * kNTILES;
    const int TI = tb / kTJ;
    const int TJ = tb - TI * kTJ;
    const int tid = threadIdx.x;

    const int p = pair & 1;
    const float* Fc = fld + (p * kNSHOTS + s) * 5 * kNG;
    float*       Fn = fld + ((1 - p) * kNSHOTS + s) * 5 * kNG;

    // float4 base of the loaded tile origin (guarded row TI*16, col TJ*16)
    const int base4 = TI * kINT * kGC4 + TJ * (kINT / 4);

    // ---- stage fields + moduli into LDS, fully coalesced, ONE barrier ----
    {
        const int gsrc = base4 + (tid >> 3) * kGC4 + (tid & 7);
        float4* L4 = (float4*)LBUF;
#pragma unroll
        for (int a = 0; a < 5; ++a)
            L4[a * (kTT / 4) + tid] = ((const float4*)(Fc + (size_t)a * kNG))[gsrc];
#pragma unroll
        for (int a = 0; a < 5; ++a)
            L4[(5 + a) * (kTT / 4) + tid] = ((const float4*)(ws + (size_t)a * kNG))[gsrc];
    }

    const int id  = Shot_ids[s];
    const int sxp = kNPML + 20 + id * ((kNX - 40) / kNSHOTS);
    float st[kT];
#pragma unroll
    for (int k = 0; k < kT; ++k) st[k] = Stf[id * kNSTEPS + kT * pair + k] * kDT;

    const int ty = tid >> 4;                   // 0..15
    const int tx = tid & 15;
    const int lr0 = 2 * ty;
    const int lc0 = 2 * tx;
    const int lbase = lr0 * kTILE + lc0;

    __syncthreads();

    // ---- pull 2x2 patch (fields + moduli) into registers ----
    float vx[2][2], vz[2][2], sxx[2][2], szz[2][2], sxz[2][2];
    float rdtr[2][2], rdamp[2][2], rlam[2][2], rmu[2][2], rl2m[2][2];
    float smf[2][2], recm[2][2];
#pragma unroll
    for (int r = 0; r < 2; ++r) {
#pragma unroll
        for (int c = 0; c < 2; ++c) {
            const int l = lbase + r * kTILE + c;
            vx[r][c]  = Lvx[l];
            vz[r][c]  = Lvz[l];
            sxx[r][c] = Lsxx[l];
            szz[r][c] = Lszz[l];
            sxz[r][c] = Lsxz[l];
            rdtr[r][c]  = LBUF[5 * kTT + l];
            rdamp[r][c] = LBUF[6 * kTT + l];
            rlam[r][c]  = LBUF[7 * kTT + l];
            rmu[r][c]   = LBUF[8 * kTT + l];
            rl2m[r][c]  = LBUF[9 * kTT + l];
            const int prow = TI * kINT - kHALO + lr0 + r;   // padded-grid row
            const int pcol = TJ * kINT - kHALO + lc0 + c;
            smf[r][c]  = (prow == kSRC_Z && pcol == sxp) ? 1.0f : 0.0f;
            const bool inter = (lr0 + r >= kHALO) && (lr0 + r < kHALO + kINT) &&
                               (lc0 + c >= kHALO) && (lc0 + c < kHALO + kINT);
            recm[r][c] = (inter && prow == kREC_Z &&
                          (unsigned)(pcol - kNPML) < (unsigned)kNX) ? 1.0f : 0.0f;
        }
    }

    float rsum = 0.0f;
#pragma unroll
    for (int k = 0; k < kT; ++k) {
        // ---- velocity phase (reads stress LDS/regs; writes vx,vz) ----
#pragma unroll
        for (int r = 0; r < 2; ++r) {
#pragma unroll
            for (int c = 0; c < 2; ++c) {
                const int l = lbase + r * kTILE + c;
                const float sxxC = sxx[r][c];
                const float sxzC = sxz[r][c];
                const float szzC = szz[r][c];
                const float sxxR = (c < 1) ? sxx[r][c + 1] : Lsxx[l + 1];
                const float sxzU = (r > 0) ? sxz[r - 1][c] : Lsxz[l - kTILE];
                const float sxzL = (c > 0) ? sxz[r][c - 1] : Lsxz[l - 1];
                const float szzD = (r < 1) ? szz[r + 1][c] : Lszz[l + kTILE];
                const float nvx = (vx[r][c] + rdtr[r][c] * ((sxxR - sxxC) + (sxzC - sxzU))) * rdamp[r][c];
                const float nvz = (vz[r][c] + rdtr[r][c] * ((sxzC - sxzL) + (szzD - szzC))) * rdamp[r][c];
                vx[r][c] = nvx;
                vz[r][c] = nvz;
                rsum += recm[r][c] * nvx * nvx;
            }
        }
        // publish full velocity patch (disjoint from stress arrays -> no race)
#pragma unroll
        for (int r = 0; r < 2; ++r) {
#pragma unroll
            for (int c = 0; c < 2; ++c) {
                const int l = lbase + r * kTILE + c;
                Lvx[l] = vx[r][c];
                Lvz[l] = vz[r][c];
            }
        }
        __syncthreads();
        // ---- stress phase (reads velocity LDS/regs; writes stresses) ----
#pragma unroll
        for (int r = 0; r < 2; ++r) {
#pragma unroll
            for (int c = 0; c < 2; ++c) {
                const int l = lbase + r * kTILE + c;
                const float vxC = vx[r][c];
                const float vzC = vz[r][c];
                const float vxL = (c > 0) ? vx[r][c - 1] : Lvx[l - 1];
                const float vxD = (r < 1) ? vx[r + 1][c] : Lvx[l + kTILE];
                const float vzU = (r > 0) ? vz[r - 1][c] : Lvz[l - kTILE];
                const float vzR = (c < 1) ? vz[r][c + 1] : Lvz[l + 1];
                const float dvx = vxC - vxL;
                const float dvz = vzC - vzU;
                const float dmp = rdamp[r][c];
                float nsxx = (sxx[r][c] + (rl2m[r][c] * dvx + rlam[r][c] * dvz)) * dmp;
                float nszz = (szz[r][c] + (rlam[r][c] * dvx + rl2m[r][c] * dvz)) * dmp;
                float nsxz = (sxz[r][c] + rmu[r][c] * ((vxD - vxC) + (vzR - vzC))) * dmp;
                const float adds = smf[r][c] * st[k];
                nsxx += adds;
                nszz += adds;
                sxx[r][c] = nsxx;
                szz[r][c] = nszz;
                sxz[r][c] = nsxz;
            }
        }
        // publish full stress patch
#pragma unroll
        for (int r = 0; r < 2; ++r) {
#pragma unroll
            for (int c = 0; c < 2; ++c) {
                const int l = lbase + r * kTILE + c;
                Lsxx[l] = sxx[r][c];
                Lszz[l] = szz[r][c];
                Lsxz[l] = sxz[r][c];
            }
        }
        __syncthreads();
    }

    // LDS holds the final state. Coalesced float4 interior writeback.
    // Interior guarded origin: row = guard(8) + TI*kINT, col = guard(8) + TJ*kINT.
    {
        const int grow0 = 8 + TI * kINT;
        const int gcol4 = (8 + TJ * kINT) >> 2;        // FIXED: no extra kHALO
        for (int q = tid; q < 5 * kINT * (kINT / 4); q += 256) {   // 320
            const int f  = q >> 6;
            const int rr = (q >> 2) & 15;
            const int c4 = q & 3;
            float4* dst = (float4*)(Fn + (size_t)f * kNG);
            const float4* src = (const float4*)(LBUF + f * kTT);
            dst[(grow0 + rr) * kGC4 + gcol4 + c4] =
                src[(kHALO + rr) * (kTILE / 4) + (kHALO / 4) + c4];
        }
    }

    // one atomic per wave for the recorder energy
    for (int off = 32; off > 0; off >>= 1) rsum += __shfl_down(rsum, off, 64);
    if ((threadIdx.x & 63) == 0 && rsum != 0.0f) atomicAdd(lossp, rsum);
}

__global__ void fwi_finish_kernel(const float* __restrict__ ws,
                                  float* __restrict__ out) {
    out[0] = 0.5f * ws[25 * kNG];
}

extern "C" void kernel_launch(void* const* d_in, const int* in_sizes, int n_in,
                              void* d_out, int out_size, void* d_ws, size_t ws_size,
                              hipStream_t stream) {
    const float* Vp  = (const float*)d_in[0];
    const float* Vs  = (const float*)d_in[1];
    const float* Den = (const float*)d_in[2];
    const float* Stf = (const float*)d_in[3];
    // d_in[4] = Mask (all-ones; identity in forward value) -- unused
    const int* Shot_ids = (const int*)d_in[5];
    float* out = (float*)d_out;
    float* ws  = (float*)d_ws;

    fwi_init_kernel<<<512, 256, 0, stream>>>(Vp, Vs, Den, ws);
    for (int pair = 0; pair < kPAIRS; ++pair) {
        fwi_step_kernel<<<kBLOCKS, 256, 0, stream>>>(ws, Stf, Shot_ids, pair);
    }
    fwi_finish_kernel<<<1, 1, 0, stream>>>(ws, out);
}

// Round 8
// 864.734 us; speedup vs baseline: 1.2587x; 1.0845x over previous
//
#include <hip/hip_runtime.h>
#include <cmath>

namespace {
constexpr int kNZ = 300, kNX = 400;
constexpr int kNPML = 32;
constexpr int kNZP = 364, kNXP = 464;        // padded physical grid
constexpr int kNSTEPS = 200, kNSHOTS = 2;
constexpr int kSRC_Z = 34, kREC_Z = 34;      // NPML + 2
constexpr float kDT = 0.001f;
constexpr float kINV_DX = 100.0f;            // 1/DX

// persistent slab decomposition
constexpr int kR = 8;                         // rows per slab
constexpr int kNSLAB = 46;                    // 46*8 = 368 rows; 364..367 dead (zero moduli)
constexpr int kNB = kNSLAB - 1;               // 45 boundaries
constexpr int kBlocks = kNSHOTS * kNSLAB;     // 92 blocks, all co-resident
constexpr int kThreads = 512;                 // one column per thread (464 active)
constexpr int kPitch = 468;                   // LDS: [0]=left guard,1..464,465=right guard,+pad
constexpr int kFStride = kR * kPitch;         // 3744 floats per LDS field

// ws layout (floats / ints):
//   [0, 4096)            : int flags[shot][b][dir] padded x16  (2*45*2*16 = 2880 used)
//   [4096, 4096+167040)  : float halo[shot][b][dir][slot][464]  (slot0=velocity,slot1=stress)
//   [171136]             : loss
constexpr int kFlagStride = 16;
constexpr int kHaloBase = 4096;
constexpr int kHaloCount = kNSHOTS * kNB * 2 * 2 * kNXP;   // 167040
constexpr int kLossOff = kHaloBase + kHaloCount;           // 171136
}  // namespace

__global__ void fwi_flaginit_kernel(float* __restrict__ ws) {
    int* flags = (int*)ws;
    const int gtid = blockIdx.x * blockDim.x + threadIdx.x;
    const int gstride = gridDim.x * blockDim.x;
    for (int q = gtid; q < kHaloBase; q += gstride) flags[q] = 0;
    if (gtid == 0) ws[kLossOff] = 0.0f;
}

// Persistent kernel: the whole 200-step simulation in one dispatch.
// Slab k (rows [8k, 8k+8)) x full width. Fields in registers (per-thread
// column) + LDS (vx,vz,sxx,sxz for col+-1 exchange; szz vertical-only -> regs).
// Neighbor slabs exchange one boundary row per phase through L3 using
// agent-scope atomics + per-boundary monotonic sequence flags. No grid sync,
// no field traffic to global memory.
__global__ __launch_bounds__(kThreads, 1) void fwi_sim_kernel(
    const float* __restrict__ Vp, const float* __restrict__ Vs,
    const float* __restrict__ Den, const float* __restrict__ Stf,
    const int* __restrict__ Shot_ids, float* __restrict__ ws) {
    __shared__ float L[4 * kFStride];   // 59.9 KB
    float* Lvx  = L;
    float* Lvz  = L + kFStride;
    float* Lsxx = L + 2 * kFStride;
    float* Lsxz = L + 3 * kFStride;

    const int blk  = blockIdx.x;
    const int s    = blk / kNSLAB;
    const int slab = blk - s * kNSLAB;
    const int r0   = slab * kR;
    const int tid  = threadIdx.x;
    const bool active = tid < kNXP;
    const int lc = tid + 1;

    int*   flags = (int*)ws;
    float* halo  = ws + kHaloBase;
    float* lossp = ws + kLossOff;

    // zero LDS fields
    for (int q = tid; q < 4 * kFStride; q += kThreads) L[q] = 0.0f;

    // ---- per-thread moduli for my column, rows r0..r0+7 (zero if dead) ----
    float rdtr[kR], rdamp[kR], rlam[kR], rmu[kR], rl2m[kR];
#pragma unroll
    for (int r = 0; r < kR; ++r) { rdtr[r] = rdamp[r] = rlam[r] = rmu[r] = rl2m[r] = 0.0f; }
    if (active) {
#pragma unroll
        for (int r = 0; r < kR; ++r) {
            const int i = r0 + r;
            const int j = tid;
            if (i < kNZP) {
                int iz = i - kNPML; iz = iz < 0 ? 0 : (iz > kNZ - 1 ? kNZ - 1 : iz);
                int jx = j - kNPML; jx = jx < 0 ? 0 : (jx > kNX - 1 ? kNX - 1 : jx);
                const float vp  = Vp[iz * kNX + jx];
                const float vs  = Vs[iz * kNX + jx];
                const float rho = Den[iz * kNX + jx];
                const float m = vs * vs * rho * 1e-6f;
                const float l = (vp * vp - 2.0f * vs * vs) * rho * 1e-6f;
                const float sc = kDT * kINV_DX;
                float dz = fmaxf((float)(kNPML - i), (float)(i - (kNZP - 1 - kNPML)));
                dz = fminf(fmaxf(dz, 0.0f), (float)kNPML) * (1.0f / kNPML);
                float dxx = fmaxf((float)(kNPML - j), (float)(j - (kNXP - 1 - kNPML)));
                dxx = fminf(fmaxf(dxx, 0.0f), (float)kNPML) * (1.0f / kNPML);
                rdamp[r] = expf(-0.1f * (dz * dz + dxx * dxx));
                rdtr[r]  = kDT / rho * kINV_DX;
                rlam[r]  = l * sc;
                rmu[r]   = m * sc;
                rl2m[r]  = (l + 2.0f * m) * sc;
            }
        }
    }

    const int id  = Shot_ids[s];
    const int sxp = kNPML + 20 + id * ((kNX - 40) / kNSHOTS);
    const float* stf = Stf + id * kNSTEPS;
    const int rsrc = kSRC_Z - r0;     // in [0,8) only for slab 4
    const int rrec = kREC_Z - r0;
    const float srcm = (active && tid == sxp) ? 1.0f : 0.0f;
    const float recm = (active && (unsigned)(tid - kNPML) < (unsigned)kNX) ? 1.0f : 0.0f;

    // flag pointers (monotonic seq: velocity of step t -> 2t+1, stress -> 2t+2)
    // dir0 = data flowing DOWN (written by upper slab b), dir1 = UP (by slab b+1)
    const bool hasTop = (slab > 0);
    const bool hasBot = (slab < kNSLAB - 1);
    int* ftopw = hasTop ? &flags[((s * kNB + (slab - 1)) * 2 + 1) * kFlagStride] : nullptr;
    int* fbotw = hasBot ? &flags[((s * kNB + slab) * 2 + 0) * kFlagStride] : nullptr;
    int* ftopr = hasTop ? &flags[((s * kNB + (slab - 1)) * 2 + 0) * kFlagStride] : nullptr;
    int* fbotr = hasBot ? &flags[((s * kNB + slab) * 2 + 1) * kFlagStride] : nullptr;
    // halo rows: halo[s][b][dir][slot][col], slot0 = velocity, slot1 = stress
    auto hrow = [&](int b, int dir, int slot) {
        return halo + (((s * kNB + b) * 2 + dir) * 2 + slot) * kNXP;
    };
    float* hTopDownV = hasTop ? hrow(slab - 1, 0, 0) : nullptr;  // read vz from top
    float* hTopDownS = hasTop ? hrow(slab - 1, 0, 1) : nullptr;  // read sxz from top
    float* hTopUpV   = hasTop ? hrow(slab - 1, 1, 0) : nullptr;  // write my vx row0 up
    float* hTopUpS   = hasTop ? hrow(slab - 1, 1, 1) : nullptr;  // write my szz row0 up
    float* hBotDownV = hasBot ? hrow(slab, 0, 0) : nullptr;      // write my vz row7 down
    float* hBotDownS = hasBot ? hrow(slab, 0, 1) : nullptr;      // write my sxz row7 down
    float* hBotUpV   = hasBot ? hrow(slab, 1, 0) : nullptr;      // read vx from bottom
    float* hBotUpS   = hasBot ? hrow(slab, 1, 1) : nullptr;      // read szz from bottom

    float fvx[kR]  = {}, fvz[kR]  = {}, fsxx[kR] = {}, fszz[kR] = {}, fsxz[kR] = {};
    float rsum = 0.0f;
    __syncthreads();

    for (int t = 0; t < kNSTEPS; ++t) {
        // ======== phase A: velocity ========
        if (t > 0) {
            const int want = 2 * t;   // neighbors' stress flags of step t-1
            if (tid == 0 && hasTop) {
                while (__hip_atomic_load(ftopr, __ATOMIC_RELAXED, __HIP_MEMORY_SCOPE_AGENT) < want) {}
            }
            if (tid == 1 && hasBot) {
                while (__hip_atomic_load(fbotr, __ATOMIC_RELAXED, __HIP_MEMORY_SCOPE_AGENT) < want) {}
            }
        }
        __syncthreads();
        float sxzTop = 0.0f, szzBot = 0.0f;
        if (active && t > 0) {
            if (hasTop) sxzTop = __hip_atomic_load(&hTopDownS[tid], __ATOMIC_RELAXED, __HIP_MEMORY_SCOPE_AGENT);
            if (hasBot) szzBot = __hip_atomic_load(&hBotUpS[tid],  __ATOMIC_RELAXED, __HIP_MEMORY_SCOPE_AGENT);
        }
        if (active) {
#pragma unroll
            for (int r = 0; r < kR; ++r) {
                const float sxxC = fsxx[r];
                const float sxzC = fsxz[r];
                const float szzC = fszz[r];
                const float sxxR = Lsxx[r * kPitch + lc + 1];
                const float sxzL = Lsxz[r * kPitch + lc - 1];
                const float sxzU = (r > 0) ? fsxz[r - 1] : sxzTop;
                const float szzD = (r < kR - 1) ? fszz[r + 1] : szzBot;
                const float nvx = (fvx[r] + rdtr[r] * ((sxxR - sxxC) + (sxzC - sxzU))) * rdamp[r];
                const float nvz = (fvz[r] + rdtr[r] * ((sxzC - sxzL) + (szzD - szzC))) * rdamp[r];
                fvx[r] = nvx;
                fvz[r] = nvz;
                Lvx[r * kPitch + lc] = nvx;
                Lvz[r * kPitch + lc] = nvz;
                if (r == rrec) rsum += recm * nvx * nvx;
            }
            if (hasTop) __hip_atomic_store(&hTopUpV[tid],   fvx[0],      __ATOMIC_RELAXED, __HIP_MEMORY_SCOPE_AGENT);
            if (hasBot) __hip_atomic_store(&hBotDownV[tid], fvz[kR - 1], __ATOMIC_RELAXED, __HIP_MEMORY_SCOPE_AGENT);
        }
        __syncthreads();   // drains vmem (halo stores) + orders LDS writes
        if (tid == 0 && hasTop) __hip_atomic_store(ftopw, 2 * t + 1, __ATOMIC_RELAXED, __HIP_MEMORY_SCOPE_AGENT);
        if (tid == 1 && hasBot) __hip_atomic_store(fbotw, 2 * t + 1, __ATOMIC_RELAXED, __HIP_MEMORY_SCOPE_AGENT);

        // ======== phase B: stress ========
        {
            const int want = 2 * t + 1;   // neighbors' velocity flags of step t
            if (tid == 0 && hasTop) {
                while (__hip_atomic_load(ftopr, __ATOMIC_RELAXED, __HIP_MEMORY_SCOPE_AGENT) < want) {}
            }
            if (tid == 1 && hasBot) {
                while (__hip_atomic_load(fbotr, __ATOMIC_RELAXED, __HIP_MEMORY_SCOPE_AGENT) < want) {}
            }
        }
        __syncthreads();
        if (active) {
            float vzTop = 0.0f, vxBot = 0.0f;
            if (hasTop) vzTop = __hip_atomic_load(&hTopDownV[tid], __ATOMIC_RELAXED, __HIP_MEMORY_SCOPE_AGENT);
            if (hasBot) vxBot = __hip_atomic_load(&hBotUpV[tid],  __ATOMIC_RELAXED, __HIP_MEMORY_SCOPE_AGENT);
            const float sval = stf[t] * kDT;
#pragma unroll
            for (int r = 0; r < kR; ++r) {
                const float vxC = fvx[r];
                const float vzC = fvz[r];
                const float vxL = Lvx[r * kPitch + lc - 1];
                const float vzR = Lvz[r * kPitch + lc + 1];
                const float vzU = (r > 0) ? fvz[r - 1] : vzTop;
                const float vxD = (r < kR - 1) ? fvx[r + 1] : vxBot;
                const float dvx = vxC - vxL;
                const float dvz = vzC - vzU;
                float nsxx = (fsxx[r] + (rl2m[r] * dvx + rlam[r] * dvz)) * rdamp[r];
                float nszz = (fszz[r] + (rlam[r] * dvx + rl2m[r] * dvz)) * rdamp[r];
                float nsxz = (fsxz[r] + rmu[r] * ((vxD - vxC) + (vzR - vzC))) * rdamp[r];
                if (r == rsrc) { nsxx += srcm * sval; nszz += srcm * sval; }
                fsxx[r] = nsxx;
                fszz[r] = nszz;
                fsxz[r] = nsxz;
                Lsxx[r * kPitch + lc] = nsxx;
                Lsxz[r * kPitch + lc] = nsxz;
            }
            if (hasTop) __hip_atomic_store(&hTopUpS[tid],   fszz[0],      __ATOMIC_RELAXED, __HIP_MEMORY_SCOPE_AGENT);
            if (hasBot) __hip_atomic_store(&hBotDownS[tid], fsxz[kR - 1], __ATOMIC_RELAXED, __HIP_MEMORY_SCOPE_AGENT);
        }
        __syncthreads();
        if (tid == 0 && hasTop) __hip_atomic_store(ftopw, 2 * t + 2, __ATOMIC_RELAXED, __HIP_MEMORY_SCOPE_AGENT);
        if (tid == 1 && hasBot) __hip_atomic_store(fbotw, 2 * t + 2, __ATOMIC_RELAXED, __HIP_MEMORY_SCOPE_AGENT);
    }

    // ---- loss: one atomic per wave ----
    for (int off = 32; off > 0; off >>= 1) rsum += __shfl_down(rsum, off, 64);
    if ((tid & 63) == 0 && rsum != 0.0f) atomicAdd(lossp, rsum);
}

__global__ void fwi_finish_kernel(const float* __restrict__ ws,
                                  float* __restrict__ out) {
    out[0] = 0.5f * ws[kLossOff];
}

extern "C" void kernel_launch(void* const* d_in, const int* in_sizes, int n_in,
                              void* d_out, int out_size, void* d_ws, size_t ws_size,
                              hipStream_t stream) {
    const float* Vp  = (const float*)d_in[0];
    const float* Vs  = (const float*)d_in[1];
    const float* Den = (const float*)d_in[2];
    const float* Stf = (const float*)d_in[3];
    // d_in[4] = Mask (all-ones; identity in forward value) -- unused
    const int* Shot_ids = (const int*)d_in[5];
    float* out = (float*)d_out;
    float* ws  = (float*)d_ws;

    fwi_flaginit_kernel<<<16, 256, 0, stream>>>(ws);
    void* args[] = {(void*)&Vp, (void*)&Vs, (void*)&Den, (void*)&Stf,
                    (void*)&Shot_ids, (void*)&ws};
    hipLaunchCooperativeKernel((const void*)fwi_sim_kernel, dim3(kBlocks),
                               dim3(kThreads), args, 0, stream);
    fwi_finish_kernel<<<1, 1, 0, stream>>>(ws, out);
}

// Round 9
// 751.525 us; speedup vs baseline: 1.4483x; 1.1506x over previous
//
#include <hip/hip_runtime.h>
#include <cmath>

namespace {
constexpr int kNZ = 300, kNX = 400;
constexpr int kNPML = 32;
constexpr int kNZP = 364, kNXP = 464;        // padded physical grid
constexpr int kNSTEPS = 200, kNSHOTS = 2;
constexpr int kSRC_Z = 34, kREC_Z = 34;      // NPML + 2
constexpr float kDT = 0.001f;
constexpr float kINV_DX = 100.0f;            // 1/DX

// persistent slab decomposition
constexpr int kR = 8;                         // rows per slab
constexpr int kNSLAB = 46;                    // 368 rows; 364..367 dead (zero moduli)
constexpr int kNB = kNSLAB - 1;               // 45 boundaries
constexpr int kBlocks = kNSHOTS * kNSLAB;     // 92 blocks, all co-resident
constexpr int kThreads = 512;                 // one column per thread (464 active)
constexpr int kPitch = 468;                   // LDS row pitch (guard cols 0 and 465)
constexpr int kFStride = kR * kPitch;         // 3744 floats per LDS field

// ws layout (floats / ints):
//   [0, 4096)    : int flags[shot][b][dir] padded x16
//   [4096, ...)  : float halo[buf][shot][b][dir][slot(6)][464]   (double-buffered)
//   loss         : 1 float after halos
constexpr int kFlagStride = 16;
constexpr int kHaloBase = 4096;
constexpr int kHaloCount = 2 * kNSHOTS * kNB * 2 * 6 * kNXP;   // 1,002,240
constexpr int kLossOff = kHaloBase + kHaloCount;
}  // namespace

__global__ void fwi_flaginit_kernel(float* __restrict__ ws) {
    const int gtid = blockIdx.x * blockDim.x + threadIdx.x;
    const int gstride = gridDim.x * blockDim.x;
    for (int q = gtid; q <= kLossOff; q += gstride) ws[q] = 0.0f;
}

// Persistent kernel, ONE neighbor sync per timestep (fused velocity+stress).
// Slab k = rows [8k, 8k+8) x full width; per-thread column in registers, LDS
// for col+-1 exchange. Each step: wait neighbor flag(t-1 data), redundantly
// compute velocity at rows -1 and 8 from the 2-row halo, then own velocities,
// then own stresses, then publish 6 halo rows/direction (double-buffered by
// step parity) + monotonic flag. No grid sync, no field traffic to global.
__global__ __launch_bounds__(kThreads, 1) void fwi_sim_kernel(
    const float* __restrict__ Vp, const float* __restrict__ Vs,
    const float* __restrict__ Den, const float* __restrict__ Stf,
    const int* __restrict__ Shot_ids, float* __restrict__ ws) {
    __shared__ float L[4 * kFStride];   // 59904 B
    float* Lvx  = L;
    float* Lvz  = L + kFStride;
    float* Lsxx = L + 2 * kFStride;
    float* Lsxz = L + 3 * kFStride;

    const int blk  = blockIdx.x;
    const int s    = blk / kNSLAB;
    const int slab = blk - s * kNSLAB;
    const int r0   = slab * kR;
    const int tid  = threadIdx.x;
    const bool active = tid < kNXP;
    const int lc = tid + 1;

    int*   flags = (int*)ws;
    float* halo  = ws + kHaloBase;
    float* lossp = ws + kLossOff;

    for (int q = tid; q < 4 * kFStride; q += kThreads) L[q] = 0.0f;

    // ---- moduli for my column: rows 0..7 plus rows -1 and 8 (dtr/damp) ----
    auto modAt = [&](int i, int j, float& dtr_, float& dmp_, float& lam_,
                     float& mu_, float& l2m_) {
        dtr_ = dmp_ = lam_ = mu_ = l2m_ = 0.0f;
        if (i >= 0 && i < kNZP && j >= 0 && j < kNXP) {
            int iz = i - kNPML; iz = iz < 0 ? 0 : (iz > kNZ - 1 ? kNZ - 1 : iz);
            int jx = j - kNPML; jx = jx < 0 ? 0 : (jx > kNX - 1 ? kNX - 1 : jx);
            const float vp  = Vp[iz * kNX + jx];
            const float vs  = Vs[iz * kNX + jx];
            const float rho = Den[iz * kNX + jx];
            const float m = vs * vs * rho * 1e-6f;
            const float l = (vp * vp - 2.0f * vs * vs) * rho * 1e-6f;
            const float sc = kDT * kINV_DX;
            float dz = fmaxf((float)(kNPML - i), (float)(i - (kNZP - 1 - kNPML)));
            dz = fminf(fmaxf(dz, 0.0f), (float)kNPML) * (1.0f / kNPML);
            float dxx = fmaxf((float)(kNPML - j), (float)(j - (kNXP - 1 - kNPML)));
            dxx = fminf(fmaxf(dxx, 0.0f), (float)kNPML) * (1.0f / kNPML);
            dmp_ = expf(-0.1f * (dz * dz + dxx * dxx));
            dtr_ = kDT / rho * kINV_DX;
            lam_ = l * sc;
            mu_  = m * sc;
            l2m_ = (l + 2.0f * m) * sc;
        }
    };
    float rdtr[kR], rdamp[kR], rlam[kR], rmu[kR], rl2m[kR];
    float dtrT = 0, dmpT = 0, dtrB = 0, dmpB = 0;
    if (active) {
#pragma unroll
        for (int r = 0; r < kR; ++r)
            modAt(r0 + r, tid, rdtr[r], rdamp[r], rlam[r], rmu[r], rl2m[r]);
        float dum0, dum1, dum2;
        modAt(r0 - 1, tid, dtrT, dmpT, dum0, dum1, dum2);
        modAt(r0 + kR, tid, dtrB, dmpB, dum0, dum1, dum2);
    }

    const int id  = Shot_ids[s];
    const int sxp = kNPML + 20 + id * ((kNX - 40) / kNSHOTS);
    const float* stf = Stf + id * kNSTEPS;
    const int rsrc = kSRC_Z - r0;
    const int rrec = kREC_Z - r0;
    const float srcm = (active && tid == sxp) ? 1.0f : 0.0f;
    const float recm = (active && (unsigned)(tid - kNPML) < (unsigned)kNX) ? 1.0f : 0.0f;

    const bool hasTop = (slab > 0);
    const bool hasBot = (slab < kNSLAB - 1);
    // flags: dir0 = top slab of boundary writes (data flows down), dir1 = up
    int* ftopw = hasTop ? &flags[((s * kNB + (slab - 1)) * 2 + 1) * kFlagStride] : nullptr;
    int* fbotw = hasBot ? &flags[((s * kNB + slab) * 2 + 0) * kFlagStride] : nullptr;
    int* ftopr = hasTop ? &flags[((s * kNB + (slab - 1)) * 2 + 0) * kFlagStride] : nullptr;
    int* fbotr = hasBot ? &flags[((s * kNB + slab) * 2 + 1) * kFlagStride] : nullptr;
    // halo row base: [buf][s][b][dir][slot][col]
    auto hbase = [&](int buf, int b, int dir) {
        return halo + ((((buf * kNSHOTS + s) * kNB + b) * 2 + dir) * 6) * kNXP;
    };

    float fvx[kR]  = {}, fvz[kR]  = {}, fsxx[kR] = {}, fszz[kR] = {}, fsxz[kR] = {};
    float rsum = 0.0f;
    __syncthreads();

    for (int t = 0; t < kNSTEPS; ++t) {
        const int rb = (t & 1) ^ 1;        // read buffer (step t-1 data)
        const int wb = t & 1;              // write buffer (step t data)
        // ---- wait for neighbors' step t-1 data ----
        if (tid == 0 && hasTop) {
            while (__hip_atomic_load(ftopr, __ATOMIC_RELAXED, __HIP_MEMORY_SCOPE_AGENT) < t) {}
        }
        if (tid == 1 && hasBot) {
            while (__hip_atomic_load(fbotr, __ATOMIC_RELAXED, __HIP_MEMORY_SCOPE_AGENT) < t) {}
        }
        __syncthreads();

        // ---- load halo (state t-1). dir0 slots: vx7,vz7,sxx7,szz7,sxz7,sxz6
        //                              dir1 slots: vx0,vz0,sxx0,sxz0,szz0,szz1
        float h_vxT = 0, h_vzT = 0, h_sxxT = 0, h_szzT = 0, h_sxzT = 0, h_sxz2T = 0;
        float h_sxxT_r = 0, h_sxzT_l = 0;
        float h_vxB = 0, h_vzB = 0, h_sxxB = 0, h_sxzB = 0, h_szzB = 0, h_szz2B = 0;
        float h_sxxB_r = 0, h_sxzB_l = 0;
        if (active && hasTop) {
            const float* hb = hbase(rb, slab - 1, 0);
            h_vxT   = __hip_atomic_load(hb + tid,             __ATOMIC_RELAXED, __HIP_MEMORY_SCOPE_AGENT);
            h_vzT   = __hip_atomic_load(hb + kNXP + tid,      __ATOMIC_RELAXED, __HIP_MEMORY_SCOPE_AGENT);
            h_sxxT  = __hip_atomic_load(hb + 2 * kNXP + tid,  __ATOMIC_RELAXED, __HIP_MEMORY_SCOPE_AGENT);
            h_szzT  = __hip_atomic_load(hb + 3 * kNXP + tid,  __ATOMIC_RELAXED, __HIP_MEMORY_SCOPE_AGENT);
            h_sxzT  = __hip_atomic_load(hb + 4 * kNXP + tid,  __ATOMIC_RELAXED, __HIP_MEMORY_SCOPE_AGENT);
            h_sxz2T = __hip_atomic_load(hb + 5 * kNXP + tid,  __ATOMIC_RELAXED, __HIP_MEMORY_SCOPE_AGENT);
            if (tid < kNXP - 1) h_sxxT_r = __hip_atomic_load(hb + 2 * kNXP + tid + 1, __ATOMIC_RELAXED, __HIP_MEMORY_SCOPE_AGENT);
            if (tid > 0)        h_sxzT_l = __hip_atomic_load(hb + 4 * kNXP + tid - 1, __ATOMIC_RELAXED, __HIP_MEMORY_SCOPE_AGENT);
        }
        if (active && hasBot) {
            const float* hb = hbase(rb, slab, 1);
            h_vxB   = __hip_atomic_load(hb + tid,             __ATOMIC_RELAXED, __HIP_MEMORY_SCOPE_AGENT);
            h_vzB   = __hip_atomic_load(hb + kNXP + tid,      __ATOMIC_RELAXED, __HIP_MEMORY_SCOPE_AGENT);
            h_sxxB  = __hip_atomic_load(hb + 2 * kNXP + tid,  __ATOMIC_RELAXED, __HIP_MEMORY_SCOPE_AGENT);
            h_sxzB  = __hip_atomic_load(hb + 3 * kNXP + tid,  __ATOMIC_RELAXED, __HIP_MEMORY_SCOPE_AGENT);
            h_szzB  = __hip_atomic_load(hb + 4 * kNXP + tid,  __ATOMIC_RELAXED, __HIP_MEMORY_SCOPE_AGENT);
            h_szz2B = __hip_atomic_load(hb + 5 * kNXP + tid,  __ATOMIC_RELAXED, __HIP_MEMORY_SCOPE_AGENT);
            if (tid < kNXP - 1) h_sxxB_r = __hip_atomic_load(hb + 2 * kNXP + tid + 1, __ATOMIC_RELAXED, __HIP_MEMORY_SCOPE_AGENT);
            if (tid > 0)        h_sxzB_l = __hip_atomic_load(hb + 3 * kNXP + tid - 1, __ATOMIC_RELAXED, __HIP_MEMORY_SCOPE_AGENT);
        }

        // ---- velocity(t): redundant rows -1 and 8, plus own rows 0..7 ----
        float nvxT = 0, nvzT = 0, nvxB = 0, nvzB = 0;
        if (active) {
            nvxT = (h_vxT + dtrT * ((h_sxxT_r - h_sxxT) + (h_sxzT - h_sxz2T))) * dmpT;
            nvzT = (h_vzT + dtrT * ((h_sxzT - h_sxzT_l) + (fszz[0] - h_szzT))) * dmpT;
            nvxB = (h_vxB + dtrB * ((h_sxxB_r - h_sxxB) + (h_sxzB - fsxz[kR - 1]))) * dmpB;
            nvzB = (h_vzB + dtrB * ((h_sxzB - h_sxzB_l) + (h_szz2B - h_szzB))) * dmpB;
#pragma unroll
            for (int r = 0; r < kR; ++r) {
                const float sxxC = fsxx[r];
                const float sxzC = fsxz[r];
                const float szzC = fszz[r];
                const float sxxR = Lsxx[r * kPitch + lc + 1];
                const float sxzL = Lsxz[r * kPitch + lc - 1];
                const float sxzU = (r > 0) ? fsxz[r - 1] : h_sxzT;
                const float szzD = (r < kR - 1) ? fszz[r + 1] : h_szzB;
                const float nvx = (fvx[r] + rdtr[r] * ((sxxR - sxxC) + (sxzC - sxzU))) * rdamp[r];
                const float nvz = (fvz[r] + rdtr[r] * ((sxzC - sxzL) + (szzD - szzC))) * rdamp[r];
                fvx[r] = nvx;
                fvz[r] = nvz;
                Lvx[r * kPitch + lc] = nvx;
                Lvz[r * kPitch + lc] = nvz;
                if (r == rrec) rsum += recm * nvx * nvx;
            }
        }
        __syncthreads();

        // ---- stress(t): own rows 0..7; source; publish halos ----
        if (active) {
            const float sval = stf[t] * kDT;
#pragma unroll
            for (int r = 0; r < kR; ++r) {
                const float vxC = fvx[r];
                const float vzC = fvz[r];
                const float vxL = Lvx[r * kPitch + lc - 1];
                const float vzR = Lvz[r * kPitch + lc + 1];
                const float vzU = (r > 0) ? fvz[r - 1] : nvzT;
                const float vxD = (r < kR - 1) ? fvx[r + 1] : nvxB;
                const float dvx = vxC - vxL;
                const float dvz = vzC - vzU;
                float nsxx = (fsxx[r] + (rl2m[r] * dvx + rlam[r] * dvz)) * rdamp[r];
                float nszz = (fszz[r] + (rlam[r] * dvx + rl2m[r] * dvz)) * rdamp[r];
                float nsxz = (fsxz[r] + rmu[r] * ((vxD - vxC) + (vzR - vzC))) * rdamp[r];
                if (r == rsrc) { nsxx += srcm * sval; nszz += srcm * sval; }
                fsxx[r] = nsxx;
                fszz[r] = nszz;
                fsxz[r] = nsxz;
                Lsxx[r * kPitch + lc] = nsxx;
                Lsxz[r * kPitch + lc] = nsxz;
            }
            if (hasTop) {   // send my rows 0,1 upward (dir1)
                float* hb = hbase(wb, slab - 1, 1);
                __hip_atomic_store(hb + tid,            fvx[0],  __ATOMIC_RELAXED, __HIP_MEMORY_SCOPE_AGENT);
                __hip_atomic_store(hb + kNXP + tid,     fvz[0],  __ATOMIC_RELAXED, __HIP_MEMORY_SCOPE_AGENT);
                __hip_atomic_store(hb + 2 * kNXP + tid, fsxx[0], __ATOMIC_RELAXED, __HIP_MEMORY_SCOPE_AGENT);
                __hip_atomic_store(hb + 3 * kNXP + tid, fsxz[0], __ATOMIC_RELAXED, __HIP_MEMORY_SCOPE_AGENT);
                __hip_atomic_store(hb + 4 * kNXP + tid, fszz[0], __ATOMIC_RELAXED, __HIP_MEMORY_SCOPE_AGENT);
                __hip_atomic_store(hb + 5 * kNXP + tid, fszz[1], __ATOMIC_RELAXED, __HIP_MEMORY_SCOPE_AGENT);
            }
            if (hasBot) {   // send my rows 6,7 downward (dir0)
                float* hb = hbase(wb, slab, 0);
                __hip_atomic_store(hb + tid,            fvx[kR - 1],  __ATOMIC_RELAXED, __HIP_MEMORY_SCOPE_AGENT);
                __hip_atomic_store(hb + kNXP + tid,     fvz[kR - 1],  __ATOMIC_RELAXED, __HIP_MEMORY_SCOPE_AGENT);
                __hip_atomic_store(hb + 2 * kNXP + tid, fsxx[kR - 1], __ATOMIC_RELAXED, __HIP_MEMORY_SCOPE_AGENT);
                __hip_atomic_store(hb + 3 * kNXP + tid, fszz[kR - 1], __ATOMIC_RELAXED, __HIP_MEMORY_SCOPE_AGENT);
                __hip_atomic_store(hb + 4 * kNXP + tid, fsxz[kR - 1], __ATOMIC_RELAXED, __HIP_MEMORY_SCOPE_AGENT);
                __hip_atomic_store(hb + 5 * kNXP + tid, fsxz[kR - 2], __ATOMIC_RELAXED, __HIP_MEMORY_SCOPE_AGENT);
            }
        }
        __syncthreads();   // drains halo stores (vmcnt) before flag publish
        if (tid == 0 && hasTop) __hip_atomic_store(ftopw, t + 1, __ATOMIC_RELAXED, __HIP_MEMORY_SCOPE_AGENT);
        if (tid == 1 && hasBot) __hip_atomic_store(fbotw, t + 1, __ATOMIC_RELAXED, __HIP_MEMORY_SCOPE_AGENT);
    }

    for (int off = 32; off > 0; off >>= 1) rsum += __shfl_down(rsum, off, 64);
    if ((tid & 63) == 0 && rsum != 0.0f) atomicAdd(lossp, rsum);
}

__global__ void fwi_finish_kernel(const float* __restrict__ ws,
                                  float* __restrict__ out) {
    out[0] = 0.5f * ws[kLossOff];
}

extern "C" void kernel_launch(void* const* d_in, const int* in_sizes, int n_in,
                              void* d_out, int out_size, void* d_ws, size_t ws_size,
                              hipStream_t stream) {
    const float* Vp  = (const float*)d_in[0];
    const float* Vs  = (const float*)d_in[1];
    const float* Den = (const float*)d_in[2];
    const float* Stf = (const float*)d_in[3];
    // d_in[4] = Mask (all-ones; identity in forward value) -- unused
    const int* Shot_ids = (const int*)d_in[5];
    float* out = (float*)d_out;
    float* ws  = (float*)d_ws;

    fwi_flaginit_kernel<<<64, 256, 0, stream>>>(ws);
    void* args[] = {(void*)&Vp, (void*)&Vs, (void*)&Den, (void*)&Stf,
                    (void*)&Shot_ids, (void*)&ws};
    hipLaunchCooperativeKernel((const void*)fwi_sim_kernel, dim3(kBlocks),
                               dim3(kThreads), args, 0, stream);
    fwi_finish_kernel<<<1, 1, 0, stream>>>(ws, out);
}